// Round 2
// baseline (423.650 us; speedup 1.0000x reference)
//
#include <hip/hip_runtime.h>
#include <math.h>

#define N_SAMPLES 2048
#define E_EDGES   4096
#define NSPLIT    32
#define ROWS_PER  (N_SAMPLES / NSPLIT)   // 64

// ---------------- Kernel A: split-K partials of bo = Ro^T X, bi = Ri^T X ----
__global__ __launch_bounds__(256) void k_partial(const float* __restrict__ Ri,
                                                 const float* __restrict__ Ro,
                                                 const float* __restrict__ X,
                                                 float* __restrict__ pbo,
                                                 float* __restrict__ pbi) {
    const int ec = blockIdx.x;   // 0..3  (1024-column chunk)
    const int ns = blockIdx.y;   // 0..31 (64-row chunk)
    const int t  = threadIdx.x;
    const float4* Ri4 = reinterpret_cast<const float4*>(Ri);
    const float4* Ro4 = reinterpret_cast<const float4*>(Ro);
    const float4* X4  = reinterpret_cast<const float4*>(X);

    float abo[4][4], abi[4][4];
#pragma unroll
    for (int c = 0; c < 4; ++c)
#pragma unroll
        for (int d = 0; d < 4; ++d) { abo[c][d] = 0.f; abi[c][d] = 0.f; }

    const int v = ec * 256 + t;  // float4 column index (0..1023)
    const int n0 = ns * ROWS_PER;
    for (int n = n0; n < n0 + ROWS_PER; ++n) {
        float4 xv = X4[n];
        float4 ro = Ro4[(size_t)n * 1024 + v];
        float4 ri = Ri4[(size_t)n * 1024 + v];
        float xs[4]  = {xv.x, xv.y, xv.z, xv.w};
        float ros[4] = {ro.x, ro.y, ro.z, ro.w};
        float ris[4] = {ri.x, ri.y, ri.z, ri.w};
#pragma unroll
        for (int c = 0; c < 4; ++c)
#pragma unroll
            for (int d = 0; d < 4; ++d) {
                abo[c][d] += ros[c] * xs[d];
                abi[c][d] += ris[c] * xs[d];
            }
    }

    float4* pbo4 = reinterpret_cast<float4*>(pbo);
    float4* pbi4 = reinterpret_cast<float4*>(pbi);
#pragma unroll
    for (int c = 0; c < 4; ++c) {
        size_t idx = (size_t)ns * E_EDGES + 4 * (size_t)v + c;  // per-e float4
        pbo4[idx] = make_float4(abo[c][0], abo[c][1], abo[c][2], abo[c][3]);
        pbi4[idx] = make_float4(abi[c][0], abi[c][1], abi[c][2], abi[c][3]);
    }
}

// ---------------- Kernel B: reduce partials -> bo, bi (float4 per e) --------
__global__ __launch_bounds__(256) void k_reduce(const float* __restrict__ pbo,
                                                const float* __restrict__ pbi,
                                                float* __restrict__ bo,
                                                float* __restrict__ bi) {
    const int e = blockIdx.x * 256 + threadIdx.x;   // 0..4095
    const float4* pbo4 = reinterpret_cast<const float4*>(pbo);
    const float4* pbi4 = reinterpret_cast<const float4*>(pbi);
    double so[4] = {0, 0, 0, 0}, si[4] = {0, 0, 0, 0};
    for (int ns = 0; ns < NSPLIT; ++ns) {
        float4 a = pbo4[(size_t)ns * E_EDGES + e];
        float4 b = pbi4[(size_t)ns * E_EDGES + e];
        so[0] += a.x; so[1] += a.y; so[2] += a.z; so[3] += a.w;
        si[0] += b.x; si[1] += b.y; si[2] += b.z; si[3] += b.w;
    }
    reinterpret_cast<float4*>(bo)[e] =
        make_float4((float)so[0], (float)so[1], (float)so[2], (float)so[3]);
    reinterpret_cast<float4*>(bi)[e] =
        make_float4((float)si[0], (float)si[1], (float)si[2], (float)si[3]);
}

// ============================================================================
// Kernel C: one sample per 64-thread wave; 4096-amp state entirely in VGPRs.
// Amp index = (lane[6 bits] , slot[6 bits]).
//   reg  bits: w1->R5 w2->R4 w4->R3 w5->R2 w6->R1 w9->R0   (slot bit)
//   lane bits: w0->mask32 w3->mask16 w7->mask8 w8->mask4 w10->mask2 w11->mask1
// ============================================================================

struct U3C { float u00, u01r, u01i, u10r, u10i, u11r, u11i; };

__device__ __forceinline__ U3C mkU3(const float* __restrict__ th, int a) {
    float T = th[a], P = th[a + 1], L = th[a + 2];
    float st, ct;   sincosf(0.5f * T, &st, &ct);
    float sl, cl;   sincosf(L, &sl, &cl);
    float sp, cp;   sincosf(P, &sp, &cp);
    float spl, cpl; sincosf(P + L, &spl, &cpl);
    U3C u;
    u.u00  = ct;
    u.u01r = -cl * st; u.u01i = -sl * st;
    u.u10r =  cp * st; u.u10i =  sp * st;
    u.u11r = cpl * ct; u.u11i = spl * ct;
    return u;
}

template<int RB>
__device__ __forceinline__ void u3_reg(float (&ar)[64], float (&ai)[64], const U3C u) {
#pragma unroll
    for (int s0 = 0; s0 < 64; ++s0) {
        if (s0 & (1 << RB)) continue;
        const int s1 = s0 | (1 << RB);
        float a0r = ar[s0], a0i = ai[s0], a1r = ar[s1], a1i = ai[s1];
        ar[s0] = u.u00 * a0r + u.u01r * a1r - u.u01i * a1i;
        ai[s0] = u.u00 * a0i + u.u01r * a1i + u.u01i * a1r;
        ar[s1] = u.u10r * a0r - u.u10i * a0i + u.u11r * a1r - u.u11i * a1i;
        ai[s1] = u.u10r * a0i + u.u10i * a0r + u.u11r * a1i + u.u11i * a1r;
    }
}

template<int MASK>
__device__ __forceinline__ void u3_lane(float (&ar)[64], float (&ai)[64],
                                        const U3C u, int lane) {
    const bool b = (lane & MASK) != 0;
    const float ssr = b ? u.u11r : u.u00;
    const float ssi = b ? u.u11i : 0.f;
    const float spr = b ? u.u10r : u.u01r;
    const float spi = b ? u.u10i : u.u01i;
#pragma unroll
    for (int s = 0; s < 64; ++s) {
        float pr = __shfl_xor(ar[s], MASK);
        float pi = __shfl_xor(ai[s], MASK);
        float mr = ar[s], mi = ai[s];
        ar[s] = ssr * mr - ssi * mi + spr * pr - spi * pi;
        ai[s] = ssr * mi + ssi * mr + spr * pi + spi * pr;
    }
}

template<int CRB, int TRB>
__device__ __forceinline__ void cx_reg_reg(float (&ar)[64], float (&ai)[64]) {
#pragma unroll
    for (int s = 0; s < 64; ++s) {
        if ((s & (1 << CRB)) && !(s & (1 << TRB))) {
            const int p = s | (1 << TRB);
            float t;
            t = ar[s]; ar[s] = ar[p]; ar[p] = t;
            t = ai[s]; ai[s] = ai[p]; ai[p] = t;
        }
    }
}

template<int CMASK, int TRB>
__device__ __forceinline__ void cx_lane_reg(float (&ar)[64], float (&ai)[64], int lane) {
    const bool c = (lane & CMASK) != 0;
#pragma unroll
    for (int s0 = 0; s0 < 64; ++s0) {
        if (s0 & (1 << TRB)) continue;
        const int s1 = s0 | (1 << TRB);
        float n0r = c ? ar[s1] : ar[s0];
        float n1r = c ? ar[s0] : ar[s1];
        float n0i = c ? ai[s1] : ai[s0];
        float n1i = c ? ai[s0] : ai[s1];
        ar[s0] = n0r; ar[s1] = n1r; ai[s0] = n0i; ai[s1] = n1i;
    }
}

template<int CMASK, int TMASK>
__device__ __forceinline__ void cx_lane_lane(float (&ar)[64], float (&ai)[64], int lane) {
    const bool c = (lane & CMASK) != 0;
#pragma unroll
    for (int s = 0; s < 64; ++s) {
        float pr = __shfl_xor(ar[s], TMASK);
        float pi = __shfl_xor(ai[s], TMASK);
        ar[s] = c ? pr : ar[s];
        ai[s] = c ? pi : ai[s];
    }
}

__global__ __launch_bounds__(64, 2) void k_sim(const float* __restrict__ Ri,
                                               const float* __restrict__ Ro,
                                               const float* __restrict__ ev,
                                               const float* __restrict__ X,
                                               const float* __restrict__ th,
                                               const float* __restrict__ bo,
                                               const float* __restrict__ bi,
                                               float* __restrict__ out) {
    const int n    = blockIdx.x;
    const int lane = threadIdx.x;   // 64 threads = 1 wave

    // ---- mi[n][:], mo[n][:] via double accumulation over e ----
    double acc[8];
#pragma unroll
    for (int j = 0; j < 8; ++j) acc[j] = 0.0;

    const float4* Ri4 = reinterpret_cast<const float4*>(Ri + (size_t)n * E_EDGES);
    const float4* Ro4 = reinterpret_cast<const float4*>(Ro + (size_t)n * E_EDGES);
    const float4* E4  = reinterpret_cast<const float4*>(ev);
    const float4* BO  = reinterpret_cast<const float4*>(bo);
    const float4* BI  = reinterpret_cast<const float4*>(bi);
#pragma unroll 4
    for (int j = 0; j < 16; ++j) {
        int v = lane + 64 * j;
        float4 r_i = Ri4[v], r_o = Ro4[v], e4 = E4[v];
        float ri[4] = {r_i.x, r_i.y, r_i.z, r_i.w};
        float ro[4] = {r_o.x, r_o.y, r_o.z, r_o.w};
        float ee[4] = {e4.x, e4.y, e4.z, e4.w};
#pragma unroll
        for (int c = 0; c < 4; ++c) {
            float4 b_o = BO[4 * v + c], b_i = BI[4 * v + c];
            double rie = (double)(ri[c]) * (double)(ee[c]);
            double roe = (double)(ro[c]) * (double)(ee[c]);
            acc[0] += rie * b_o.x; acc[1] += rie * b_o.y;
            acc[2] += rie * b_o.z; acc[3] += rie * b_o.w;
            acc[4] += roe * b_i.x; acc[5] += roe * b_i.y;
            acc[6] += roe * b_i.z; acc[7] += roe * b_i.w;
        }
    }
    // butterfly: every lane ends with the full sums
#pragma unroll
    for (int off = 32; off >= 1; off >>= 1)
#pragma unroll
        for (int j = 0; j < 8; ++j) acc[j] += __shfl_xor(acc[j], off);

    // lane w (0..11) computes sincos(M_w / 2); static-index select chain
    double Mw = acc[0];
    Mw = (lane == 1) ? acc[1] : Mw;
    Mw = (lane == 2) ? acc[2] : Mw;
    Mw = (lane == 3) ? acc[3] : Mw;
    Mw = (lane == 4) ? acc[4] : Mw;
    Mw = (lane == 5) ? acc[5] : Mw;
    Mw = (lane == 6) ? acc[6] : Mw;
    Mw = (lane == 7) ? acc[7] : Mw;
    if (lane >= 8) Mw = (double)X[n * 4 + (lane & 3)];  // lanes 8..11 used
    double sv, cv;
    sincos(0.5 * Mw, &sv, &cv);   // double: M can be O(1000) rad
    float sCf[12], sSf[12];
#pragma unroll
    for (int w = 0; w < 12; ++w) {
        sCf[w] = __shfl((float)cv, w);
        sSf[w] = __shfl((float)sv, w);
    }

    // ---- product state ----
    // lane bits: w0->b5 w3->b4 w7->b3 w8->b2 w10->b1 w11->b0
    const float pref =
        (((lane >> 5) & 1) ? sSf[0]  : sCf[0])  *
        (((lane >> 4) & 1) ? sSf[3]  : sCf[3])  *
        (((lane >> 3) & 1) ? sSf[7]  : sCf[7])  *
        (((lane >> 2) & 1) ? sSf[8]  : sCf[8])  *
        (((lane >> 1) & 1) ? sSf[10] : sCf[10]) *
        (((lane >> 0) & 1) ? sSf[11] : sCf[11]);

    float ar[64], ai[64];
#pragma unroll
    for (int s = 0; s < 64; ++s) {
        // reg bits: w1->b5 w2->b4 w4->b3 w5->b2 w6->b1 w9->b0 (compile-time)
        float suf =
            (((s >> 5) & 1) ? sSf[1] : sCf[1]) *
            (((s >> 4) & 1) ? sSf[2] : sCf[2]) *
            (((s >> 3) & 1) ? sSf[4] : sCf[4]) *
            (((s >> 2) & 1) ? sSf[5] : sCf[5]) *
            (((s >> 1) & 1) ? sSf[6] : sCf[6]) *
            (((s >> 0) & 1) ? sSf[9] : sCf[9]);
        ar[s] = pref * suf;
        ai[s] = 0.f;
    }

    // ---- circuit ----
    U3C u;
    u = mkU3(th, 0);  u3_lane<32>(ar, ai, u, lane);   // u3 w0
    u = mkU3(th, 3);  u3_reg<5>(ar, ai, u);           // u3 w1
    cx_lane_reg<32, 5>(ar, ai, lane);                 // cx(0,1)
    u = mkU3(th, 6);  u3_reg<4>(ar, ai, u);           // u3 w2
    u = mkU3(th, 9);  u3_lane<16>(ar, ai, u, lane);   // u3 w3
    cx_lane_reg<16, 4>(ar, ai, lane);                 // cx(3,2)
    u = mkU3(th, 12); u3_reg<3>(ar, ai, u);           // u3 w4
    u = mkU3(th, 15); u3_reg<2>(ar, ai, u);           // u3 w5
    cx_reg_reg<3, 2>(ar, ai);                         // cx(4,5)
    u = mkU3(th, 18); u3_reg<1>(ar, ai, u);           // u3 w6
    u = mkU3(th, 21); u3_lane<8>(ar, ai, u, lane);    // u3 w7
    cx_lane_reg<8, 1>(ar, ai, lane);                  // cx(7,6)
    u = mkU3(th, 24); u3_lane<4>(ar, ai, u, lane);    // u3 w8
    u = mkU3(th, 27); u3_reg<0>(ar, ai, u);           // u3 w9
    cx_lane_reg<4, 0>(ar, ai, lane);                  // cx(8,9)
    u = mkU3(th, 30); u3_lane<2>(ar, ai, u, lane);    // u3 w10
    u = mkU3(th, 33); u3_lane<1>(ar, ai, u, lane);    // u3 w11
    cx_lane_lane<1, 2>(ar, ai, lane);                 // cx(11,10)
    u = mkU3(th, 36); u3_reg<5>(ar, ai, u);           // u3 w1
    u = mkU3(th, 39); u3_reg<4>(ar, ai, u);           // u3 w2
    cx_reg_reg<5, 4>(ar, ai);                         // cx(1,2)
    u = mkU3(th, 42); u3_reg<2>(ar, ai, u);           // u3 w5
    u = mkU3(th, 45); u3_reg<1>(ar, ai, u);           // u3 w6
    cx_reg_reg<1, 2>(ar, ai);                         // cx(6,5)
    u = mkU3(th, 48); u3_reg<0>(ar, ai, u);           // u3 w9
    u = mkU3(th, 51); u3_lane<2>(ar, ai, u, lane);    // u3 w10
    cx_lane_reg<2, 0>(ar, ai, lane);                  // cx(10,9)
    u = mkU3(th, 54); u3_reg<4>(ar, ai, u);           // u3 w2
    u = mkU3(th, 57); u3_reg<2>(ar, ai, u);           // u3 w5
    cx_reg_reg<4, 2>(ar, ai);                         // cx(2,5)
    u = mkU3(th, 60); u3_reg<2>(ar, ai, u);           // u3 w5
    u = mkU3(th, 63); u3_reg<0>(ar, ai, u);           // u3 w9
    cx_reg_reg<2, 0>(ar, ai);                         // cx(5,9)
    u = mkU3(th, 66); u3_reg<3>(ar, ai, u);           // u3 w4

    // ---- <Z_9>: wire 9 = reg bit 0 -> sign known at compile time ----
    float zp = 0.f;
#pragma unroll
    for (int s = 0; s < 64; ++s) {
        float m = ar[s] * ar[s] + ai[s] * ai[s];
        zp += (s & 1) ? -m : m;
    }
    double z = (double)zp;
#pragma unroll
    for (int off = 32; off >= 1; off >>= 1) z += __shfl_xor(z, off);
    if (lane == 0) out[n] = (float)(3.14159265358979323846 * (1.0 - z));
}

extern "C" void kernel_launch(void* const* d_in, const int* in_sizes, int n_in,
                              void* d_out, int out_size, void* d_ws, size_t ws_size,
                              hipStream_t stream) {
    (void)in_sizes; (void)n_in; (void)out_size; (void)ws_size;
    const float* X  = (const float*)d_in[0];
    const float* ev = (const float*)d_in[1];
    const float* Ri = (const float*)d_in[2];
    const float* Ro = (const float*)d_in[3];
    const float* th = (const float*)d_in[4];
    float* out = (float*)d_out;

    float* pbo = (float*)d_ws;                              // [NSPLIT][4096][4]
    float* pbi = pbo + (size_t)NSPLIT * E_EDGES * 4;        // [NSPLIT][4096][4]
    float* bo  = pbi + (size_t)NSPLIT * E_EDGES * 4;        // [4096][4]
    float* bi  = bo  + (size_t)E_EDGES * 4;                 // [4096][4]

    hipLaunchKernelGGL(k_partial, dim3(4, NSPLIT), dim3(256), 0, stream,
                       Ri, Ro, X, pbo, pbi);
    hipLaunchKernelGGL(k_reduce, dim3(E_EDGES / 256), dim3(256), 0, stream,
                       pbo, pbi, bo, bi);
    hipLaunchKernelGGL(k_sim, dim3(N_SAMPLES), dim3(64), 0, stream,
                       Ri, Ro, ev, X, th, bo, bi, out);
}

// Round 3
// 123.220 us; speedup vs baseline: 3.4382x; 3.4382x over previous
//
#include <hip/hip_runtime.h>
#include <math.h>

#define N_SAMPLES 2048
#define E_EDGES   4096
#define NSPLIT    32
#define ROWS_PER  (N_SAMPLES / NSPLIT)   // 64

// ---------------- Kernel A: split-K partials of bo = Ro^T X, bi = Ri^T X ----
__global__ __launch_bounds__(256) void k_partial(const float* __restrict__ Ri,
                                                 const float* __restrict__ Ro,
                                                 const float* __restrict__ X,
                                                 float* __restrict__ pbo,
                                                 float* __restrict__ pbi) {
    const int ec = blockIdx.x;   // 0..3  (1024-column chunk)
    const int ns = blockIdx.y;   // 0..31 (64-row chunk)
    const int t  = threadIdx.x;
    const float4* Ri4 = reinterpret_cast<const float4*>(Ri);
    const float4* Ro4 = reinterpret_cast<const float4*>(Ro);
    const float4* X4  = reinterpret_cast<const float4*>(X);

    float abo[4][4], abi[4][4];
#pragma unroll
    for (int c = 0; c < 4; ++c)
#pragma unroll
        for (int d = 0; d < 4; ++d) { abo[c][d] = 0.f; abi[c][d] = 0.f; }

    const int v = ec * 256 + t;  // float4 column index (0..1023)
    const int n0 = ns * ROWS_PER;
    for (int n = n0; n < n0 + ROWS_PER; ++n) {
        float4 xv = X4[n];
        float4 ro = Ro4[(size_t)n * 1024 + v];
        float4 ri = Ri4[(size_t)n * 1024 + v];
        float xs[4]  = {xv.x, xv.y, xv.z, xv.w};
        float ros[4] = {ro.x, ro.y, ro.z, ro.w};
        float ris[4] = {ri.x, ri.y, ri.z, ri.w};
#pragma unroll
        for (int c = 0; c < 4; ++c)
#pragma unroll
            for (int d = 0; d < 4; ++d) {
                abo[c][d] += ros[c] * xs[d];
                abi[c][d] += ris[c] * xs[d];
            }
    }

    float4* pbo4 = reinterpret_cast<float4*>(pbo);
    float4* pbi4 = reinterpret_cast<float4*>(pbi);
#pragma unroll
    for (int c = 0; c < 4; ++c) {
        size_t idx = (size_t)ns * E_EDGES + 4 * (size_t)v + c;  // per-e float4
        pbo4[idx] = make_float4(abo[c][0], abo[c][1], abo[c][2], abo[c][3]);
        pbi4[idx] = make_float4(abi[c][0], abi[c][1], abi[c][2], abi[c][3]);
    }
}

// ---------------- Kernel B: reduce partials -> bo, bi (float4 per e) --------
__global__ __launch_bounds__(256) void k_reduce(const float* __restrict__ pbo,
                                                const float* __restrict__ pbi,
                                                float* __restrict__ bo,
                                                float* __restrict__ bi) {
    const int e = blockIdx.x * 256 + threadIdx.x;   // 0..4095
    const float4* pbo4 = reinterpret_cast<const float4*>(pbo);
    const float4* pbi4 = reinterpret_cast<const float4*>(pbi);
    double so[4] = {0, 0, 0, 0}, si[4] = {0, 0, 0, 0};
    for (int ns = 0; ns < NSPLIT; ++ns) {
        float4 a = pbo4[(size_t)ns * E_EDGES + e];
        float4 b = pbi4[(size_t)ns * E_EDGES + e];
        so[0] += a.x; so[1] += a.y; so[2] += a.z; so[3] += a.w;
        si[0] += b.x; si[1] += b.y; si[2] += b.z; si[3] += b.w;
    }
    reinterpret_cast<float4*>(bo)[e] =
        make_float4((float)so[0], (float)so[1], (float)so[2], (float)so[3]);
    reinterpret_cast<float4*>(bi)[e] =
        make_float4((float)si[0], (float)si[1], (float)si[2], (float)si[3]);
}

// ============================================================================
// Kernel C v3: one sample per 256-thread block (4 waves). 16 complex amps per
// thread (32 VGPRs). First u3 layer folded into the product state.
// Amp bit map (12 bits):
//   wave bits: wv bit1 = w0, wv bit0 = w3            (controls only -> free)
//   lane bits: b5=w4 b4=w6 b3=w7 b2=w8 b1=w10 b0=w11 (shuffle gates)
//   reg  bits: b3=w1 b2=w2 b1=w5 b0=w9               (register gates)
// ============================================================================

struct CF { float r, i; };
__device__ __forceinline__ CF cmul(CF a, CF b) {
    return { a.r * b.r - a.i * b.i, a.r * b.i + a.i * b.r };
}

struct U3C { float u00, u01r, u01i, u10r, u10i, u11r, u11i; };

__device__ __forceinline__ U3C mkU3(const float* __restrict__ th, int a) {
    float T = th[a], P = th[a + 1], L = th[a + 2];
    float st, ct;   sincosf(0.5f * T, &st, &ct);
    float sl, cl;   sincosf(L, &sl, &cl);
    float sp, cp;   sincosf(P, &sp, &cp);
    float spl, cpl; sincosf(P + L, &spl, &cpl);
    U3C u;
    u.u00  = ct;
    u.u01r = -cl * st; u.u01i = -sl * st;
    u.u10r =  cp * st; u.u10i =  sp * st;
    u.u11r = cpl * ct; u.u11i = spl * ct;
    return u;
}

template<int RB>
__device__ __forceinline__ void u3_reg(float (&ar)[16], float (&ai)[16], const U3C u) {
#pragma unroll
    for (int s0 = 0; s0 < 16; ++s0) {
        if (s0 & (1 << RB)) continue;
        const int s1 = s0 | (1 << RB);
        float a0r = ar[s0], a0i = ai[s0], a1r = ar[s1], a1i = ai[s1];
        ar[s0] = u.u00 * a0r + u.u01r * a1r - u.u01i * a1i;
        ai[s0] = u.u00 * a0i + u.u01r * a1i + u.u01i * a1r;
        ar[s1] = u.u10r * a0r - u.u10i * a0i + u.u11r * a1r - u.u11i * a1i;
        ai[s1] = u.u10r * a0i + u.u10i * a0r + u.u11r * a1i + u.u11i * a1r;
    }
}

template<int MASK>
__device__ __forceinline__ void u3_lane(float (&ar)[16], float (&ai)[16],
                                        const U3C u, int lane) {
    const bool b = (lane & MASK) != 0;
    const float ssr = b ? u.u11r : u.u00;
    const float ssi = b ? u.u11i : 0.f;
    const float spr = b ? u.u10r : u.u01r;
    const float spi = b ? u.u10i : u.u01i;
#pragma unroll
    for (int s = 0; s < 16; ++s) {
        float pr = __shfl_xor(ar[s], MASK);
        float pi = __shfl_xor(ai[s], MASK);
        float mr = ar[s], mi = ai[s];
        ar[s] = ssr * mr - ssi * mi + spr * pr - spi * pi;
        ai[s] = ssr * mi + ssi * mr + spr * pi + spi * pr;
    }
}

// CNOT, target = reg bit TRB, control = per-thread runtime predicate
template<int TRB>
__device__ __forceinline__ void cx_pred_reg(float (&ar)[16], float (&ai)[16], bool c) {
#pragma unroll
    for (int s0 = 0; s0 < 16; ++s0) {
        if (s0 & (1 << TRB)) continue;
        const int s1 = s0 | (1 << TRB);
        float n0r = c ? ar[s1] : ar[s0];
        float n1r = c ? ar[s0] : ar[s1];
        float n0i = c ? ai[s1] : ai[s0];
        float n1i = c ? ai[s0] : ai[s1];
        ar[s0] = n0r; ar[s1] = n1r; ai[s0] = n0i; ai[s1] = n1i;
    }
}

// CNOT, control = reg bit CRB, target = reg bit TRB (compile-time rename)
template<int CRB, int TRB>
__device__ __forceinline__ void cx_reg_reg(float (&ar)[16], float (&ai)[16]) {
#pragma unroll
    for (int s = 0; s < 16; ++s) {
        if ((s & (1 << CRB)) && !(s & (1 << TRB))) {
            const int p = s | (1 << TRB);
            float t;
            t = ar[s]; ar[s] = ar[p]; ar[p] = t;
            t = ai[s]; ai[s] = ai[p]; ai[p] = t;
        }
    }
}

// CNOT, control = lane bit CMASK, target = lane bit TMASK
template<int CMASK, int TMASK>
__device__ __forceinline__ void cx_lane_lane(float (&ar)[16], float (&ai)[16], int lane) {
    const bool c = (lane & CMASK) != 0;
#pragma unroll
    for (int s = 0; s < 16; ++s) {
        float pr = __shfl_xor(ar[s], TMASK);
        float pi = __shfl_xor(ai[s], TMASK);
        ar[s] = c ? pr : ar[s];
        ai[s] = c ? pi : ai[s];
    }
}

__global__ __launch_bounds__(256, 2) void k_sim(const float* __restrict__ Ri,
                                                const float* __restrict__ Ro,
                                                const float* __restrict__ ev,
                                                const float* __restrict__ X,
                                                const float* __restrict__ th,
                                                const float* __restrict__ bo,
                                                const float* __restrict__ bi,
                                                float* __restrict__ out) {
    __shared__ double redM[4][8];
    __shared__ float  fac[12][4];   // per-wire folded factor: A.r A.i B.r B.i
    __shared__ float  su3[11][8];   // second-layer u3 coeffs
    __shared__ double zred[4];

    const int n    = blockIdx.x;
    const int t    = threadIdx.x;   // 0..255
    const int lane = t & 63;
    const int wv   = t >> 6;        // bit1 = wire0, bit0 = wire3

    // ---- per-thread fp32 partial of mi/mo over 16 edges ----
    float accf[8];
#pragma unroll
    for (int j = 0; j < 8; ++j) accf[j] = 0.f;

    const float4* Ri4 = reinterpret_cast<const float4*>(Ri + (size_t)n * E_EDGES);
    const float4* Ro4 = reinterpret_cast<const float4*>(Ro + (size_t)n * E_EDGES);
    const float4* E4  = reinterpret_cast<const float4*>(ev);
    const float4* BO  = reinterpret_cast<const float4*>(bo);
    const float4* BI  = reinterpret_cast<const float4*>(bi);
#pragma unroll
    for (int k = 0; k < 4; ++k) {
        int v = t + 256 * k;
        float4 r_i = Ri4[v], r_o = Ro4[v], e4 = E4[v];
        float ri[4] = {r_i.x, r_i.y, r_i.z, r_i.w};
        float ro[4] = {r_o.x, r_o.y, r_o.z, r_o.w};
        float ee[4] = {e4.x, e4.y, e4.z, e4.w};
#pragma unroll
        for (int c = 0; c < 4; ++c) {
            float4 b_o = BO[4 * v + c], b_i = BI[4 * v + c];
            float rie = ri[c] * ee[c];
            float roe = ro[c] * ee[c];
            accf[0] += rie * b_o.x; accf[1] += rie * b_o.y;
            accf[2] += rie * b_o.z; accf[3] += rie * b_o.w;
            accf[4] += roe * b_i.x; accf[5] += roe * b_i.y;
            accf[6] += roe * b_i.z; accf[7] += roe * b_i.w;
        }
    }
    // in-wave butterfly reduce in double
    double accd[8];
#pragma unroll
    for (int j = 0; j < 8; ++j) accd[j] = (double)accf[j];
#pragma unroll
    for (int off = 32; off >= 1; off >>= 1)
#pragma unroll
        for (int j = 0; j < 8; ++j) accd[j] += __shfl_xor(accd[j], off);
    if (lane == 0)
#pragma unroll
        for (int j = 0; j < 8; ++j) redM[wv][j] = accd[j];
    __syncthreads();

    // ---- folded first-layer factors (t<12) and second-layer coeffs (t<23) --
    if (t < 12) {
        double Mw = (t < 8)
            ? (redM[0][t] + redM[1][t] + redM[2][t] + redM[3][t])
            : (double)X[n * 4 + (t - 8)];
        double sv, cv;
        sincos(0.5 * Mw, &sv, &cv);   // double: M can be O(1000) rad
        float c = (float)cv, s = (float)sv;
        U3C u = mkU3(th, 3 * t);
        fac[t][0] = u.u00 * c + u.u01r * s;   // A = u00*c + u01*s
        fac[t][1] = u.u01i * s;
        fac[t][2] = u.u10r * c + u.u11r * s;  // B = u10*c + u11*s
        fac[t][3] = u.u10i * c + u.u11i * s;
    } else if (t < 23) {
        int g = t - 12;
        U3C u = mkU3(th, 36 + 3 * g);
        su3[g][0] = u.u00;  su3[g][1] = u.u01r; su3[g][2] = u.u01i;
        su3[g][3] = u.u10r; su3[g][4] = u.u10i; su3[g][5] = u.u11r;
        su3[g][6] = u.u11i;
    }
    __syncthreads();

    // ---- initial amplitudes: product of folded factors ----
    CF pref;
    {
        auto ldf = [&](int w, int bit) -> CF {
            return CF{ fac[w][bit ? 2 : 0], fac[w][bit ? 3 : 1] };
        };
        pref = ldf(0, (wv >> 1) & 1);
        pref = cmul(pref, ldf(3,  wv        & 1));
        pref = cmul(pref, ldf(4, (lane >> 5) & 1));
        pref = cmul(pref, ldf(6, (lane >> 4) & 1));
        pref = cmul(pref, ldf(7, (lane >> 3) & 1));
        pref = cmul(pref, ldf(8, (lane >> 2) & 1));
        pref = cmul(pref, ldf(10,(lane >> 1) & 1));
        pref = cmul(pref, ldf(11, lane       & 1));
    }
    CF f1[2] = { {fac[1][0], fac[1][1]}, {fac[1][2], fac[1][3]} };
    CF f2[2] = { {fac[2][0], fac[2][1]}, {fac[2][2], fac[2][3]} };
    CF f5[2] = { {fac[5][0], fac[5][1]}, {fac[5][2], fac[5][3]} };
    CF f9[2] = { {fac[9][0], fac[9][1]}, {fac[9][2], fac[9][3]} };
    CF m12[4], m59[4];
#pragma unroll
    for (int a = 0; a < 2; ++a)
#pragma unroll
        for (int b = 0; b < 2; ++b) {
            m12[a * 2 + b] = cmul(f1[a], f2[b]);
            m59[a * 2 + b] = cmul(f5[a], f9[b]);
        }
    float ar[16], ai[16];
#pragma unroll
    for (int s = 0; s < 16; ++s) {
        CF v = cmul(pref, cmul(m12[s >> 2], m59[s & 3]));
        ar[s] = v.r; ai[s] = v.i;
    }

    // ---- circuit (first layer already folded) ----
    auto ldu = [&](int g) -> U3C {
        U3C u;
        u.u00  = su3[g][0]; u.u01r = su3[g][1]; u.u01i = su3[g][2];
        u.u10r = su3[g][3]; u.u10i = su3[g][4]; u.u11r = su3[g][5];
        u.u11i = su3[g][6];
        return u;
    };

    cx_pred_reg<3>(ar, ai, ((wv >> 1) & 1) != 0);   // cx(0,1)
    cx_pred_reg<2>(ar, ai, (wv & 1) != 0);          // cx(3,2)
    cx_pred_reg<1>(ar, ai, (lane & 32) != 0);       // cx(4,5)
    cx_lane_lane<8, 16>(ar, ai, lane);              // cx(7,6)
    cx_pred_reg<0>(ar, ai, (lane & 4) != 0);        // cx(8,9)
    cx_lane_lane<1, 2>(ar, ai, lane);               // cx(11,10)
    u3_reg<3>(ar, ai, ldu(0));                      // u3 w1  @36
    u3_reg<2>(ar, ai, ldu(1));                      // u3 w2  @39
    cx_reg_reg<3, 2>(ar, ai);                       // cx(1,2)
    u3_reg<1>(ar, ai, ldu(2));                      // u3 w5  @42
    u3_lane<16>(ar, ai, ldu(3), lane);              // u3 w6  @45
    cx_pred_reg<1>(ar, ai, (lane & 16) != 0);       // cx(6,5)
    u3_reg<0>(ar, ai, ldu(4));                      // u3 w9  @48
    u3_lane<2>(ar, ai, ldu(5), lane);               // u3 w10 @51
    cx_pred_reg<0>(ar, ai, (lane & 2) != 0);        // cx(10,9)
    u3_reg<2>(ar, ai, ldu(6));                      // u3 w2  @54
    u3_reg<1>(ar, ai, ldu(7));                      // u3 w5  @57
    cx_reg_reg<2, 1>(ar, ai);                       // cx(2,5)
    u3_reg<1>(ar, ai, ldu(8));                      // u3 w5  @60
    u3_reg<0>(ar, ai, ldu(9));                      // u3 w9  @63
    cx_reg_reg<1, 0>(ar, ai);                       // cx(5,9)
    u3_lane<32>(ar, ai, ldu(10), lane);             // u3 w4  @66

    // ---- <Z_9>: wire 9 = reg bit 0 (compile-time sign) ----
    float zp = 0.f;
#pragma unroll
    for (int s = 0; s < 16; ++s) {
        float m = ar[s] * ar[s] + ai[s] * ai[s];
        zp += (s & 1) ? -m : m;
    }
    double z = (double)zp;
#pragma unroll
    for (int off = 32; off >= 1; off >>= 1) z += __shfl_xor(z, off);
    if (lane == 0) zred[wv] = z;
    __syncthreads();
    if (t == 0) {
        double zt = zred[0] + zred[1] + zred[2] + zred[3];
        out[n] = (float)(3.14159265358979323846 * (1.0 - zt));
    }
}

extern "C" void kernel_launch(void* const* d_in, const int* in_sizes, int n_in,
                              void* d_out, int out_size, void* d_ws, size_t ws_size,
                              hipStream_t stream) {
    (void)in_sizes; (void)n_in; (void)out_size; (void)ws_size;
    const float* X  = (const float*)d_in[0];
    const float* ev = (const float*)d_in[1];
    const float* Ri = (const float*)d_in[2];
    const float* Ro = (const float*)d_in[3];
    const float* th = (const float*)d_in[4];
    float* out = (float*)d_out;

    float* pbo = (float*)d_ws;                              // [NSPLIT][4096][4]
    float* pbi = pbo + (size_t)NSPLIT * E_EDGES * 4;        // [NSPLIT][4096][4]
    float* bo  = pbi + (size_t)NSPLIT * E_EDGES * 4;        // [4096][4]
    float* bi  = bo  + (size_t)E_EDGES * 4;                 // [4096][4]

    hipLaunchKernelGGL(k_partial, dim3(4, NSPLIT), dim3(256), 0, stream,
                       Ri, Ro, X, pbo, pbi);
    hipLaunchKernelGGL(k_reduce, dim3(E_EDGES / 256), dim3(256), 0, stream,
                       pbo, pbi, bo, bi);
    hipLaunchKernelGGL(k_sim, dim3(N_SAMPLES), dim3(256), 0, stream,
                       Ri, Ro, ev, X, th, bo, bi, out);
}

// Round 4
// 55.015 us; speedup vs baseline: 7.7007x; 2.2398x over previous
//
#include <hip/hip_runtime.h>
#include <math.h>

#define N_SAMPLES 2048
#define E_EDGES   4096
#define NSPLIT    32

// ---------------- Kernel A: split-K partials of bo = Ro^T X, bi = Ri^T X ----
// grid (8, 32): 256 blocks. Each block: 128 float4-cols x 64 rows, with the
// 64 rows split 2-way across thread halves and combined through padded LDS.
__global__ __launch_bounds__(256) void k_partial(const float* __restrict__ Ri,
                                                 const float* __restrict__ Ro,
                                                 const float* __restrict__ X,
                                                 float* __restrict__ pbo,
                                                 float* __restrict__ pbi) {
    __shared__ float comb[128][33];   // padded: bank = (col + j) % 32, conflict-free

    const int ec   = blockIdx.x;      // 0..7  (128 float4-col chunk)
    const int ns   = blockIdx.y;      // 0..31 (64-row chunk)
    const int t    = threadIdx.x;
    const int col  = t & 127;         // local float4 col
    const int half = t >> 7;          // 0/1 row-half
    const int v    = ec * 128 + col;  // global float4 col (0..1023)

    const float4* Ri4 = reinterpret_cast<const float4*>(Ri);
    const float4* Ro4 = reinterpret_cast<const float4*>(Ro);
    const float4* X4  = reinterpret_cast<const float4*>(X);

    float abo[4][4], abi[4][4];
#pragma unroll
    for (int c = 0; c < 4; ++c)
#pragma unroll
        for (int d = 0; d < 4; ++d) { abo[c][d] = 0.f; abi[c][d] = 0.f; }

    const int n0 = ns * 64 + half * 32;
    for (int n = n0; n < n0 + 32; ++n) {
        float4 xv = X4[n];
        float4 ro = Ro4[(size_t)n * 1024 + v];
        float4 ri = Ri4[(size_t)n * 1024 + v];
        float xs[4]  = {xv.x, xv.y, xv.z, xv.w};
        float ros[4] = {ro.x, ro.y, ro.z, ro.w};
        float ris[4] = {ri.x, ri.y, ri.z, ri.w};
#pragma unroll
        for (int c = 0; c < 4; ++c)
#pragma unroll
            for (int d = 0; d < 4; ++d) {
                abo[c][d] += ros[c] * xs[d];
                abi[c][d] += ris[c] * xs[d];
            }
    }

    if (half) {
#pragma unroll
        for (int c = 0; c < 4; ++c)
#pragma unroll
            for (int d = 0; d < 4; ++d) {
                comb[col][c * 4 + d]      = abo[c][d];
                comb[col][16 + c * 4 + d] = abi[c][d];
            }
    }
    __syncthreads();
    if (!half) {
        float4* pbo4 = reinterpret_cast<float4*>(pbo);
        float4* pbi4 = reinterpret_cast<float4*>(pbi);
#pragma unroll
        for (int c = 0; c < 4; ++c) {
#pragma unroll
            for (int d = 0; d < 4; ++d) {
                abo[c][d] += comb[col][c * 4 + d];
                abi[c][d] += comb[col][16 + c * 4 + d];
            }
            size_t idx = (size_t)ns * E_EDGES + 4 * (size_t)v + c;
            pbo4[idx] = make_float4(abo[c][0], abo[c][1], abo[c][2], abo[c][3]);
            pbi4[idx] = make_float4(abi[c][0], abi[c][1], abi[c][2], abi[c][3]);
        }
    }
}

// ---------------- Kernel B: reduce partials -> bo, bi (float4 per e) --------
// grid (32): gid -> (mat, e)
__global__ __launch_bounds__(256) void k_reduce(const float* __restrict__ pbo,
                                                const float* __restrict__ pbi,
                                                float* __restrict__ bo,
                                                float* __restrict__ bi) {
    const int gid = blockIdx.x * 256 + threadIdx.x;   // 0..8191
    const int mat = gid >> 12;                        // 0 = bo, 1 = bi
    const int e   = gid & 4095;
    const float4* src = reinterpret_cast<const float4*>(mat ? pbi : pbo);
    float4*       dst = reinterpret_cast<float4*>(mat ? bi : bo);
    double s0 = 0, s1 = 0, s2 = 0, s3 = 0;
    for (int ns = 0; ns < NSPLIT; ++ns) {
        float4 a = src[(size_t)ns * E_EDGES + e];
        s0 += a.x; s1 += a.y; s2 += a.z; s3 += a.w;
    }
    dst[e] = make_float4((float)s0, (float)s1, (float)s2, (float)s3);
}

// ============================================================================
// Kernel C v4: TTN density-matrix contraction.
// The circuit is a tree: every CNOT's control wire is dead afterwards.
// Tracing the control:  rho_t' = p0*rho_t + p1*X rho_t X, i.e. in Bloch
// coords (x,y,z):  y_t *= z_c,  z_t *= z_c.  A u3 gate is the 3x3 Bloch
// rotation R = Rz(phi)*Ry(theta)*Rz(lam) (sample-independent).  Initial
// folded wire state: R_w * (sin M_w, 0, cos M_w).  <Z_9> = root z.
// u3@66 acts on dead wire 4 -> dropped.
// ============================================================================
__global__ __launch_bounds__(256) void k_sim(const float* __restrict__ Ri,
                                             const float* __restrict__ Ro,
                                             const float* __restrict__ ev,
                                             const float* __restrict__ X,
                                             const float* __restrict__ th,
                                             const float* __restrict__ bo,
                                             const float* __restrict__ bi,
                                             float* __restrict__ out) {
    __shared__ double redM[4][8];
    __shared__ float  R[22][9];     // gate g (theta offset 3g) -> 3x3 Bloch rot
    __shared__ float  sM[12], cM[12];

    const int n    = blockIdx.x;
    const int t    = threadIdx.x;   // 0..255
    const int lane = t & 63;
    const int wv   = t >> 6;

    // ---- Bloch rotation matrices for all 22 live u3 gates (t < 22) ----
    if (t < 22) {
        float T = th[3 * t], P = th[3 * t + 1], L = th[3 * t + 2];
        float st, ct, sp, cp, sl, cl;
        sincosf(T, &st, &ct);
        sincosf(P, &sp, &cp);
        sincosf(L, &sl, &cl);
        R[t][0] =  cp * ct * cl - sp * sl;
        R[t][1] = -cp * ct * sl - sp * cl;
        R[t][2] =  cp * st;
        R[t][3] =  sp * ct * cl + cp * sl;
        R[t][4] = -sp * ct * sl + cp * cl;
        R[t][5] =  sp * st;
        R[t][6] = -st * cl;
        R[t][7] =  st * sl;
        R[t][8] =  ct;
    }

    // ---- per-thread fp32 partial of mi/mo over 16 edges ----
    float accf[8];
#pragma unroll
    for (int j = 0; j < 8; ++j) accf[j] = 0.f;

    const float4* Ri4 = reinterpret_cast<const float4*>(Ri + (size_t)n * E_EDGES);
    const float4* Ro4 = reinterpret_cast<const float4*>(Ro + (size_t)n * E_EDGES);
    const float4* E4  = reinterpret_cast<const float4*>(ev);
    const float4* BO  = reinterpret_cast<const float4*>(bo);
    const float4* BI  = reinterpret_cast<const float4*>(bi);
#pragma unroll
    for (int k = 0; k < 4; ++k) {
        int v = t + 256 * k;
        float4 r_i = Ri4[v], r_o = Ro4[v], e4 = E4[v];
        float ri[4] = {r_i.x, r_i.y, r_i.z, r_i.w};
        float ro[4] = {r_o.x, r_o.y, r_o.z, r_o.w};
        float ee[4] = {e4.x, e4.y, e4.z, e4.w};
#pragma unroll
        for (int c = 0; c < 4; ++c) {
            float4 b_o = BO[4 * v + c], b_i = BI[4 * v + c];
            float rie = ri[c] * ee[c];
            float roe = ro[c] * ee[c];
            accf[0] += rie * b_o.x; accf[1] += rie * b_o.y;
            accf[2] += rie * b_o.z; accf[3] += rie * b_o.w;
            accf[4] += roe * b_i.x; accf[5] += roe * b_i.y;
            accf[6] += roe * b_i.z; accf[7] += roe * b_i.w;
        }
    }
    // in-wave butterfly reduce in double
    double accd[8];
#pragma unroll
    for (int j = 0; j < 8; ++j) accd[j] = (double)accf[j];
#pragma unroll
    for (int off = 32; off >= 1; off >>= 1)
#pragma unroll
        for (int j = 0; j < 8; ++j) accd[j] += __shfl_xor(accd[j], off);
    if (lane == 0)
#pragma unroll
        for (int j = 0; j < 8; ++j) redM[wv][j] = accd[j];
    __syncthreads();

    // ---- M angles: double sincos (full angle), lanes 0..11 ----
    if (t < 12) {
        double Mw = (t < 8)
            ? (redM[0][t] + redM[1][t] + redM[2][t] + redM[3][t])
            : (double)X[n * 4 + (t - 8)];
        double sv, cv;
        sincos(Mw, &sv, &cv);   // double: M can be O(1000) rad
        sM[t] = (float)sv; cM[t] = (float)cv;
    }
    __syncthreads();

    // ---- TTN Bloch-vector contraction (thread 0, ~250 FLOP) ----
    if (t == 0) {
        // z of folded init state (control-only wires)
        auto iz = [&](int g) -> float {
            return R[g][6] * sM[g] + R[g][8] * cM[g];
        };
        // full folded init Bloch vector (gate g == wire w for first layer)
        auto ivec = [&](int g, float& x, float& y, float& z) {
            x = R[g][0] * sM[g] + R[g][2] * cM[g];
            y = R[g][3] * sM[g] + R[g][5] * cM[g];
            z = R[g][6] * sM[g] + R[g][8] * cM[g];
        };
        auto rot = [&](int g, float& x, float& y, float& z) {
            float nx = R[g][0] * x + R[g][1] * y + R[g][2] * z;
            float ny = R[g][3] * x + R[g][4] * y + R[g][5] * z;
            float nz = R[g][6] * x + R[g][7] * y + R[g][8] * z;
            x = nx; y = ny; z = nz;
        };

        const float z0  = iz(0),  z3  = iz(3), z4 = iz(4);
        const float z7  = iz(7),  z8  = iz(8), z11 = iz(11);

        float x1, y1, z1;  ivec(1, x1, y1, z1);          // w1
        y1 *= z0;  z1 *= z0;          rot(12, x1, y1, z1);     // cx(0,1), u3@36

        float x2, y2, z2;  ivec(2, x2, y2, z2);          // w2
        y2 *= z3;  z2 *= z3;          rot(13, x2, y2, z2);     // cx(3,2), u3@39
        y2 *= z1;  z2 *= z1;          rot(18, x2, y2, z2);     // cx(1,2), u3@54

        float x6, y6, z6;  ivec(6, x6, y6, z6);          // w6
        y6 *= z7;  z6 *= z7;          rot(15, x6, y6, z6);     // cx(7,6), u3@45

        float x5, y5, z5;  ivec(5, x5, y5, z5);          // w5
        y5 *= z4;  z5 *= z4;          rot(14, x5, y5, z5);     // cx(4,5), u3@42
        y5 *= z6;  z5 *= z6;          rot(19, x5, y5, z5);     // cx(6,5), u3@57
        y5 *= z2;  z5 *= z2;          rot(20, x5, y5, z5);     // cx(2,5), u3@60

        float xA, yA, zA;  ivec(10, xA, yA, zA);         // w10
        yA *= z11; zA *= z11;         rot(17, xA, yA, zA);     // cx(11,10), u3@51

        float x9, y9, z9;  ivec(9, x9, y9, z9);          // w9
        y9 *= z8;  z9 *= z8;          rot(16, x9, y9, z9);     // cx(8,9), u3@48
        y9 *= zA;  z9 *= zA;          rot(21, x9, y9, z9);     // cx(10,9), u3@63
        z9 *= z5;                                              // cx(5,9)

        out[n] = (float)(3.14159265358979323846 * (1.0 - (double)z9));
    }
}

extern "C" void kernel_launch(void* const* d_in, const int* in_sizes, int n_in,
                              void* d_out, int out_size, void* d_ws, size_t ws_size,
                              hipStream_t stream) {
    (void)in_sizes; (void)n_in; (void)out_size; (void)ws_size;
    const float* X  = (const float*)d_in[0];
    const float* ev = (const float*)d_in[1];
    const float* Ri = (const float*)d_in[2];
    const float* Ro = (const float*)d_in[3];
    const float* th = (const float*)d_in[4];
    float* out = (float*)d_out;

    float* pbo = (float*)d_ws;                              // [NSPLIT][4096][4]
    float* pbi = pbo + (size_t)NSPLIT * E_EDGES * 4;        // [NSPLIT][4096][4]
    float* bo  = pbi + (size_t)NSPLIT * E_EDGES * 4;        // [4096][4]
    float* bi  = bo  + (size_t)E_EDGES * 4;                 // [4096][4]

    hipLaunchKernelGGL(k_partial, dim3(8, NSPLIT), dim3(256), 0, stream,
                       Ri, Ro, X, pbo, pbi);
    hipLaunchKernelGGL(k_reduce, dim3(32), dim3(256), 0, stream,
                       pbo, pbi, bo, bi);
    hipLaunchKernelGGL(k_sim, dim3(N_SAMPLES), dim3(256), 0, stream,
                       Ri, Ro, ev, X, th, bo, bi, out);
}

// Round 5
// 41.128 us; speedup vs baseline: 10.3007x; 1.3376x over previous
//
#include <hip/hip_runtime.h>
#include <math.h>

#define N_SAMPLES 2048
#define E_EDGES   4096
#define NSPLIT    32

// ---------------- Kernel A: split-K partials of bo = Ro^T X, bi = Ri^T X ----
// grid (8, 32): 256 blocks. Each block: 128 float4-cols x 64 rows, with the
// 64 rows split 2-way across thread halves and combined through padded LDS.
__global__ __launch_bounds__(256) void k_partial(const float* __restrict__ Ri,
                                                 const float* __restrict__ Ro,
                                                 const float* __restrict__ X,
                                                 float* __restrict__ pbo,
                                                 float* __restrict__ pbi) {
    __shared__ float comb[128][33];   // padded: conflict-free

    const int ec   = blockIdx.x;      // 0..7  (128 float4-col chunk)
    const int ns   = blockIdx.y;      // 0..31 (64-row chunk)
    const int t    = threadIdx.x;
    const int col  = t & 127;         // local float4 col
    const int half = t >> 7;          // 0/1 row-half
    const int v    = ec * 128 + col;  // global float4 col (0..1023)

    const float4* Ri4 = reinterpret_cast<const float4*>(Ri);
    const float4* Ro4 = reinterpret_cast<const float4*>(Ro);
    const float4* X4  = reinterpret_cast<const float4*>(X);

    float abo[4][4], abi[4][4];
#pragma unroll
    for (int c = 0; c < 4; ++c)
#pragma unroll
        for (int d = 0; d < 4; ++d) { abo[c][d] = 0.f; abi[c][d] = 0.f; }

    const int n0 = ns * 64 + half * 32;
    for (int n = n0; n < n0 + 32; ++n) {
        float4 xv = X4[n];
        float4 ro = Ro4[(size_t)n * 1024 + v];
        float4 ri = Ri4[(size_t)n * 1024 + v];
        float xs[4]  = {xv.x, xv.y, xv.z, xv.w};
        float ros[4] = {ro.x, ro.y, ro.z, ro.w};
        float ris[4] = {ri.x, ri.y, ri.z, ri.w};
#pragma unroll
        for (int c = 0; c < 4; ++c)
#pragma unroll
            for (int d = 0; d < 4; ++d) {
                abo[c][d] += ros[c] * xs[d];
                abi[c][d] += ris[c] * xs[d];
            }
    }

    if (half) {
#pragma unroll
        for (int c = 0; c < 4; ++c)
#pragma unroll
            for (int d = 0; d < 4; ++d) {
                comb[col][c * 4 + d]      = abo[c][d];
                comb[col][16 + c * 4 + d] = abi[c][d];
            }
    }
    __syncthreads();
    if (!half) {
        float4* pbo4 = reinterpret_cast<float4*>(pbo);
        float4* pbi4 = reinterpret_cast<float4*>(pbi);
#pragma unroll
        for (int c = 0; c < 4; ++c) {
#pragma unroll
            for (int d = 0; d < 4; ++d) {
                abo[c][d] += comb[col][c * 4 + d];
                abi[c][d] += comb[col][16 + c * 4 + d];
            }
            size_t idx = (size_t)ns * E_EDGES + 4 * (size_t)v + c;
            pbo4[idx] = make_float4(abo[c][0], abo[c][1], abo[c][2], abo[c][3]);
            pbi4[idx] = make_float4(abi[c][0], abi[c][1], abi[c][2], abi[c][3]);
        }
    }
}

// ---------------- Kernel B: reduce partials -> boT, biT (d-major, e-folded) -
// boT[d][e] = e[e] * bo[e][d]   (so k_sim's loads are e-contiguous per d and
// the edge-weight multiply is pre-applied once instead of 2048x).
__global__ __launch_bounds__(256) void k_reduce(const float* __restrict__ pbo,
                                                const float* __restrict__ pbi,
                                                const float* __restrict__ ev,
                                                float* __restrict__ boT,
                                                float* __restrict__ biT) {
    const int gid = blockIdx.x * 256 + threadIdx.x;   // 0..8191
    const int mat = gid >> 12;                        // 0 = bo, 1 = bi
    const int e   = gid & 4095;
    const float4* src = reinterpret_cast<const float4*>(mat ? pbi : pbo);
    float*        dst = mat ? biT : boT;
    double s0 = 0, s1 = 0, s2 = 0, s3 = 0;
    for (int ns = 0; ns < NSPLIT; ++ns) {
        float4 a = src[(size_t)ns * E_EDGES + e];
        s0 += a.x; s1 += a.y; s2 += a.z; s3 += a.w;
    }
    const float w = ev[e];
    dst[0 * E_EDGES + e] = w * (float)s0;
    dst[1 * E_EDGES + e] = w * (float)s1;
    dst[2 * E_EDGES + e] = w * (float)s2;
    dst[3 * E_EDGES + e] = w * (float)s3;
}

// ============================================================================
// Kernel C v5: TTN density-matrix contraction, coalesced boT/biT loads.
// mi[n][d] = sum_e Ri[n][e] * boT[d][e];  mo[n][d] = sum_e Ro[n][e] * biT[d][e]
// ============================================================================
__global__ __launch_bounds__(256) void k_sim(const float* __restrict__ Ri,
                                             const float* __restrict__ Ro,
                                             const float* __restrict__ X,
                                             const float* __restrict__ th,
                                             const float* __restrict__ boT,
                                             const float* __restrict__ biT,
                                             float* __restrict__ out) {
    __shared__ double redM[4][8];
    __shared__ float  R[22][9];     // gate g (theta offset 3g) -> 3x3 Bloch rot
    __shared__ float  sM[12], cM[12];

    const int n    = blockIdx.x;
    const int t    = threadIdx.x;   // 0..255
    const int lane = t & 63;
    const int wv   = t >> 6;

    // ---- Bloch rotation matrices for all 22 live u3 gates (t < 22) ----
    if (t < 22) {
        float T = th[3 * t], P = th[3 * t + 1], L = th[3 * t + 2];
        float st, ct, sp, cp, sl, cl;
        sincosf(T, &st, &ct);
        sincosf(P, &sp, &cp);
        sincosf(L, &sl, &cl);
        R[t][0] =  cp * ct * cl - sp * sl;
        R[t][1] = -cp * ct * sl - sp * cl;
        R[t][2] =  cp * st;
        R[t][3] =  sp * ct * cl + cp * sl;
        R[t][4] = -sp * ct * sl + cp * cl;
        R[t][5] =  sp * st;
        R[t][6] = -st * cl;
        R[t][7] =  st * sl;
        R[t][8] =  ct;
    }

    // ---- per-thread fp32 partial of mi/mo over 16 edges (coalesced) ----
    float accf[8];
#pragma unroll
    for (int j = 0; j < 8; ++j) accf[j] = 0.f;

    const float4* Ri4 = reinterpret_cast<const float4*>(Ri + (size_t)n * E_EDGES);
    const float4* Ro4 = reinterpret_cast<const float4*>(Ro + (size_t)n * E_EDGES);
    const float4* BO0 = reinterpret_cast<const float4*>(boT);
    const float4* BO1 = reinterpret_cast<const float4*>(boT + E_EDGES);
    const float4* BO2 = reinterpret_cast<const float4*>(boT + 2 * E_EDGES);
    const float4* BO3 = reinterpret_cast<const float4*>(boT + 3 * E_EDGES);
    const float4* BI0 = reinterpret_cast<const float4*>(biT);
    const float4* BI1 = reinterpret_cast<const float4*>(biT + E_EDGES);
    const float4* BI2 = reinterpret_cast<const float4*>(biT + 2 * E_EDGES);
    const float4* BI3 = reinterpret_cast<const float4*>(biT + 3 * E_EDGES);
#pragma unroll
    for (int k = 0; k < 4; ++k) {
        const int v = t + 256 * k;
        const float4 ri = Ri4[v], ro = Ro4[v];
        const float4 o0 = BO0[v], o1 = BO1[v], o2 = BO2[v], o3 = BO3[v];
        const float4 i0 = BI0[v], i1 = BI1[v], i2 = BI2[v], i3 = BI3[v];
        accf[0] += ri.x * o0.x + ri.y * o0.y + ri.z * o0.z + ri.w * o0.w;
        accf[1] += ri.x * o1.x + ri.y * o1.y + ri.z * o1.z + ri.w * o1.w;
        accf[2] += ri.x * o2.x + ri.y * o2.y + ri.z * o2.z + ri.w * o2.w;
        accf[3] += ri.x * o3.x + ri.y * o3.y + ri.z * o3.z + ri.w * o3.w;
        accf[4] += ro.x * i0.x + ro.y * i0.y + ro.z * i0.z + ro.w * i0.w;
        accf[5] += ro.x * i1.x + ro.y * i1.y + ro.z * i1.z + ro.w * i1.w;
        accf[6] += ro.x * i2.x + ro.y * i2.y + ro.z * i2.z + ro.w * i2.w;
        accf[7] += ro.x * i3.x + ro.y * i3.y + ro.z * i3.z + ro.w * i3.w;
    }
    // in-wave butterfly reduce in double
    double accd[8];
#pragma unroll
    for (int j = 0; j < 8; ++j) accd[j] = (double)accf[j];
#pragma unroll
    for (int off = 32; off >= 1; off >>= 1)
#pragma unroll
        for (int j = 0; j < 8; ++j) accd[j] += __shfl_xor(accd[j], off);
    if (lane == 0)
#pragma unroll
        for (int j = 0; j < 8; ++j) redM[wv][j] = accd[j];
    __syncthreads();

    // ---- M angles: double sincos (full angle), lanes 0..11 ----
    if (t < 12) {
        double Mw = (t < 8)
            ? (redM[0][t] + redM[1][t] + redM[2][t] + redM[3][t])
            : (double)X[n * 4 + (t - 8)];
        double sv, cv;
        sincos(Mw, &sv, &cv);   // double: M can be O(1000) rad
        sM[t] = (float)sv; cM[t] = (float)cv;
    }
    __syncthreads();

    // ---- TTN Bloch-vector contraction (thread 0, ~250 FLOP) ----
    if (t == 0) {
        auto iz = [&](int g) -> float {
            return R[g][6] * sM[g] + R[g][8] * cM[g];
        };
        auto ivec = [&](int g, float& x, float& y, float& z) {
            x = R[g][0] * sM[g] + R[g][2] * cM[g];
            y = R[g][3] * sM[g] + R[g][5] * cM[g];
            z = R[g][6] * sM[g] + R[g][8] * cM[g];
        };
        auto rot = [&](int g, float& x, float& y, float& z) {
            float nx = R[g][0] * x + R[g][1] * y + R[g][2] * z;
            float ny = R[g][3] * x + R[g][4] * y + R[g][5] * z;
            float nz = R[g][6] * x + R[g][7] * y + R[g][8] * z;
            x = nx; y = ny; z = nz;
        };

        const float z0  = iz(0),  z3  = iz(3), z4 = iz(4);
        const float z7  = iz(7),  z8  = iz(8), z11 = iz(11);

        float x1, y1, z1;  ivec(1, x1, y1, z1);                // w1
        y1 *= z0;  z1 *= z0;          rot(12, x1, y1, z1);     // cx(0,1), u3@36

        float x2, y2, z2;  ivec(2, x2, y2, z2);                // w2
        y2 *= z3;  z2 *= z3;          rot(13, x2, y2, z2);     // cx(3,2), u3@39
        y2 *= z1;  z2 *= z1;          rot(18, x2, y2, z2);     // cx(1,2), u3@54

        float x6, y6, z6;  ivec(6, x6, y6, z6);                // w6
        y6 *= z7;  z6 *= z7;          rot(15, x6, y6, z6);     // cx(7,6), u3@45

        float x5, y5, z5;  ivec(5, x5, y5, z5);                // w5
        y5 *= z4;  z5 *= z4;          rot(14, x5, y5, z5);     // cx(4,5), u3@42
        y5 *= z6;  z5 *= z6;          rot(19, x5, y5, z5);     // cx(6,5), u3@57
        y5 *= z2;  z5 *= z2;          rot(20, x5, y5, z5);     // cx(2,5), u3@60

        float xA, yA, zA;  ivec(10, xA, yA, zA);               // w10
        yA *= z11; zA *= z11;         rot(17, xA, yA, zA);     // cx(11,10), u3@51

        float x9, y9, z9;  ivec(9, x9, y9, z9);                // w9
        y9 *= z8;  z9 *= z8;          rot(16, x9, y9, z9);     // cx(8,9), u3@48
        y9 *= zA;  z9 *= zA;          rot(21, x9, y9, z9);     // cx(10,9), u3@63
        z9 *= z5;                                              // cx(5,9)

        out[n] = (float)(3.14159265358979323846 * (1.0 - (double)z9));
    }
}

extern "C" void kernel_launch(void* const* d_in, const int* in_sizes, int n_in,
                              void* d_out, int out_size, void* d_ws, size_t ws_size,
                              hipStream_t stream) {
    (void)in_sizes; (void)n_in; (void)out_size; (void)ws_size;
    const float* X  = (const float*)d_in[0];
    const float* ev = (const float*)d_in[1];
    const float* Ri = (const float*)d_in[2];
    const float* Ro = (const float*)d_in[3];
    const float* th = (const float*)d_in[4];
    float* out = (float*)d_out;

    float* pbo = (float*)d_ws;                              // [NSPLIT][4096][4]
    float* pbi = pbo + (size_t)NSPLIT * E_EDGES * 4;        // [NSPLIT][4096][4]
    float* boT = pbi + (size_t)NSPLIT * E_EDGES * 4;        // [4][4096]
    float* biT = boT + (size_t)4 * E_EDGES;                 // [4][4096]

    hipLaunchKernelGGL(k_partial, dim3(8, NSPLIT), dim3(256), 0, stream,
                       Ri, Ro, X, pbo, pbi);
    hipLaunchKernelGGL(k_reduce, dim3(32), dim3(256), 0, stream,
                       pbo, pbi, ev, boT, biT);
    hipLaunchKernelGGL(k_sim, dim3(N_SAMPLES), dim3(256), 0, stream,
                       Ri, Ro, X, th, boT, biT, out);
}